// Round 11
// baseline (678.662 us; speedup 1.0000x reference)
//
#include <hip/hip_runtime.h>

#define N_NODES 100000
#define N_EDGES 1600000
#define DIM 128
#define N_GRAPH 512
#define N_LAYERS 4
#define BN_EPS 1e-5f
#define GEMM_BLOCKS ((N_NODES + 127) / 128)  // 782
#define NB 512        // CSR buckets
#define BW 196        // nodes per bucket (512*196 = 100352 >= N)
#define PA_CHUNK 4096
#define TS_STRIDE 136 // ushorts per LDS row (272 B): bank-rotating, 16B-aligned

typedef __attribute__((ext_vector_type(8))) short short8;
typedef __attribute__((ext_vector_type(4))) float f32x4;

__device__ __forceinline__ float b2f(unsigned short u) {
    union { unsigned int i; float f; } x;
    x.i = ((unsigned int)u) << 16;
    return x.f;
}
__device__ __forceinline__ unsigned short f2b(float f) {
    union { float f; unsigned int i; } x;
    x.f = f;
    unsigned int r = x.i + 0x7FFFu + ((x.i >> 16) & 1u);  // RNE
    return (unsigned short)(r >> 16);
}

// ================= CSR build (bucketed, write-locality-friendly) =================
__global__ __launch_bounds__(256) void hist512_kernel(const int* __restrict__ dst,
                                                      int* __restrict__ gcnt, int E) {
    __shared__ int cnt[NB];
    int t = threadIdx.x;
    for (int i = t; i < NB; i += 256) cnt[i] = 0;
    __syncthreads();
    for (int e = blockIdx.x * 256 + t; e < E; e += 256 * 256)
        atomicAdd(&cnt[dst[e] / BW], 1);
    __syncthreads();
    for (int i = t; i < NB; i += 256)
        if (cnt[i]) atomicAdd(&gcnt[i], cnt[i]);
}

__global__ __launch_bounds__(NB) void scan512_kernel(const int* __restrict__ gcnt,
                                                     int* __restrict__ base,
                                                     int* __restrict__ gcur,
                                                     int* __restrict__ ptr) {
    __shared__ int tmp[NB];
    int t = threadIdx.x;
    int v = gcnt[t];
    tmp[t] = v;
    __syncthreads();
    int acc = v;
    for (int off = 1; off < NB; off <<= 1) {
        int add = (t >= off) ? tmp[t - off] : 0;
        __syncthreads();
        acc += add;
        tmp[t] = acc;
        __syncthreads();
    }
    int ex = acc - v;
    base[t] = ex;
    gcur[t] = ex;
    if (t == NB - 1) ptr[N_NODES] = ex + v;
}

// scatter packed (src | local_dst<<17) into bucket regions
__global__ __launch_bounds__(256) void phaseA_kernel(const int* __restrict__ src,
                                                     const int* __restrict__ dst,
                                                     int* __restrict__ gcur,
                                                     int* __restrict__ bb, int E) {
    __shared__ int cnt[NB];
    __shared__ int cur[NB];
    int t = threadIdx.x;
    int e0 = blockIdx.x * PA_CHUNK;
    for (int i = t; i < NB; i += 256) cnt[i] = 0;
    __syncthreads();
#pragma unroll
    for (int i = 0; i < PA_CHUNK / 256; i++) {
        int e = e0 + t + i * 256;
        if (e < E) atomicAdd(&cnt[dst[e] / BW], 1);
    }
    __syncthreads();
    for (int i = t; i < NB; i += 256) {
        int c = cnt[i];
        cur[i] = c ? atomicAdd(&gcur[i], c) : 0;
    }
    __syncthreads();
#pragma unroll
    for (int i = 0; i < PA_CHUNK / 256; i++) {
        int e = e0 + t + i * 256;
        if (e < E) {
            int d = dst[e];
            int b = d / BW;
            int pos = atomicAdd(&cur[b], 1);
            bb[pos] = src[e] | ((d - b * BW) << 17);
        }
    }
}

// per-bucket fine scatter; csr stores src*16 (uint4 units)
__global__ __launch_bounds__(256) void phaseB_kernel(const int* __restrict__ bb,
                                                     const int* __restrict__ base,
                                                     const int* __restrict__ gcnt,
                                                     int* __restrict__ ptr,
                                                     int* __restrict__ csr) {
    __shared__ int cnt[256];
    __shared__ int cur[256];
    __shared__ int tmp[256];
    int b = blockIdx.x, t = threadIdx.x;
    int n0 = b * BW;
    int e0 = base[b], ec = gcnt[b];
    cnt[t] = 0;
    __syncthreads();
    for (int j = t; j < ec; j += 256) atomicAdd(&cnt[bb[e0 + j] >> 17], 1);
    __syncthreads();
    int v = cnt[t];
    tmp[t] = v;
    __syncthreads();
    int acc = v;
    for (int off = 1; off < 256; off <<= 1) {
        int add = (t >= off) ? tmp[t - off] : 0;
        __syncthreads();
        acc += add;
        tmp[t] = acc;
        __syncthreads();
    }
    int ex = acc - v;
    int node = n0 + t;
    if (t < BW && node < N_NODES) ptr[node] = e0 + ex;
    cur[t] = e0 + ex;
    __syncthreads();
    for (int j = t; j < ec; j += 256) {
        int p = bb[e0 + j];
        int slot = atomicAdd(&cur[p >> 17], 1);
        csr[slot] = (p & 0x1FFFF) << 4;
    }
}

__global__ void gptr_kernel(const int* __restrict__ gid, int* __restrict__ gptr, int N, int G) {
    int g = blockIdx.x * 256 + threadIdx.x;
    if (g > G) return;
    int lo = 0, hi = N;
    while (lo < hi) {
        int mid = (lo + hi) >> 1;
        if (gid[mid] < g) lo = mid + 1; else hi = mid;
    }
    gptr[g] = lo;
}

// ================= fused f32 pool + bf16 convert (layer 0) =======================
__global__ __launch_bounds__(512) void cvtpool_kernel(const float* __restrict__ feat,
                                                      const int* __restrict__ gptr,
                                                      float* __restrict__ pooled,
                                                      ushort* __restrict__ X) {
    __shared__ float red[8][132];
    int g = blockIdx.x, t = threadIdx.x;
    int tx = t & 31, ty = t >> 5;
    int r1 = gptr[g + 1];
    float acc[4] = {0.f, 0.f, 0.f, 0.f};
    const float4* xp = (const float4*)feat;
    for (int r = gptr[g] + ty; r < r1; r += 16) {
        float4 v = xp[(size_t)r * 32 + tx];
        acc[0] += v.x; acc[1] += v.y; acc[2] += v.z; acc[3] += v.w;
        ushort4 u;
        u.x = f2b(v.x); u.y = f2b(v.y); u.z = f2b(v.z); u.w = f2b(v.w);
        ((ushort4*)X)[(size_t)r * 32 + tx] = u;
    }
#pragma unroll
    for (int j = 0; j < 4; j++) acc[j] += __shfl_xor(acc[j], 32);
    int wave = t >> 6;
    if ((ty & 1) == 0) {
#pragma unroll
        for (int j = 0; j < 4; j++) red[wave][tx * 4 + j] = acc[j];
    }
    __syncthreads();
    if (t < 128) {
        float s = 0.f;
#pragma unroll
        for (int wv = 0; wv < 8; wv++) s += red[wv][t];
        pooled[(size_t)g * 128 + t] = s;
    }
}

__global__ void cvtw_kernel(const float* __restrict__ W1, const float* __restrict__ W2,
                            ushort* __restrict__ Wt) {
    int blk = blockIdx.x;
    int mat = blk >> 7, k = blk & 127;
    int n = threadIdx.x;
    const float* W = (mat < 4) ? (W1 + (size_t)mat * 16384) : (W2 + (size_t)(mat - 4) * 16384);
    Wt[(size_t)mat * 16384 + n * 128 + k] = f2b(W[k * 128 + n]);
}

// ================= fused SpMM + GEMM1: Z = (gather X) @ W1, + column stats ========
__device__ __forceinline__ void accum8(float* acc, uint4 v) {
    unsigned w[4] = {v.x, v.y, v.z, v.w};
#pragma unroll
    for (int q = 0; q < 4; q++) {
        acc[2 * q]     += __uint_as_float(w[q] << 16);
        acc[2 * q + 1] += __uint_as_float(w[q] & 0xffff0000u);
    }
}

__global__ __launch_bounds__(256) void spmm_gemm_kernel(
    const ushort* __restrict__ X, const int* __restrict__ ptr,
    const int* __restrict__ csr, const ushort* __restrict__ Bt,
    ushort* __restrict__ Z, float* __restrict__ partial, int M) {
    __shared__ ushort Ts[128 * TS_STRIDE];
    __shared__ float lstat[256];
    int tid = threadIdx.x;
    const uint4* hp = (const uint4*)X;

    // ---- Phase 1: gather 128 dst rows into LDS (16 lanes/node, 8 nodes/slot) ----
    {
        int l = tid & 15, slot = tid >> 4;
        for (int rr = 0; rr < 8; rr++) {
            int lr = rr * 16 + slot;
            int node = blockIdx.x * 128 + lr;
            float acc[8] = {0.f, 0.f, 0.f, 0.f, 0.f, 0.f, 0.f, 0.f};
            if (node < M) {
                accum8(acc, hp[(size_t)node * 16 + l]);
                int j = ptr[node], s1 = ptr[node + 1];
                for (; j + 7 < s1; j += 8) {
                    int idx[8];
                    uint4 v[8];
#pragma unroll
                    for (int q = 0; q < 8; q++) idx[q] = csr[j + q];
#pragma unroll
                    for (int q = 0; q < 8; q++) v[q] = hp[(size_t)(idx[q] + l)];
#pragma unroll
                    for (int q = 0; q < 8; q++) accum8(acc, v[q]);
                }
                for (; j + 1 < s1; j += 2) {
                    int i0 = csr[j], i1 = csr[j + 1];
                    uint4 v0 = hp[(size_t)(i0 + l)];
                    uint4 v1 = hp[(size_t)(i1 + l)];
                    accum8(acc, v0);
                    accum8(acc, v1);
                }
                if (j < s1) accum8(acc, hp[(size_t)(csr[j] + l)]);
            }
            uint4 o;
            unsigned* op = (unsigned*)&o;
#pragma unroll
            for (int q = 0; q < 4; q++)
                op[q] = (unsigned)f2b(acc[2 * q]) | ((unsigned)f2b(acc[2 * q + 1]) << 16);
            *(uint4*)&Ts[lr * TS_STRIDE + l * 8] = o;
        }
    }
    lstat[tid] = 0.f;
    __syncthreads();

    // ---- Phase 2: MFMA from LDS (2x2 wave grid, per-ks B reload keeps VGPR low) --
    int lane = tid & 63;
    int wid = tid >> 6;
    int wr = wid >> 1, wc = wid & 1;
    int lrowBase = wr * 64;
    int colBase = wc * 64;
    int l15 = lane & 15;
    int lk = (lane >> 4) * 8;

    f32x4 acc[4][4];
#pragma unroll
    for (int m = 0; m < 4; m++)
#pragma unroll
        for (int n = 0; n < 4; n++) acc[m][n] = (f32x4){0.f, 0.f, 0.f, 0.f};

#pragma unroll 1
    for (int ks = 0; ks < 4; ks++) {
        short8 bfr[4];
#pragma unroll
        for (int n = 0; n < 4; n++)
            bfr[n] = *(const short8*)(Bt + (size_t)(colBase + n * 16 + l15) * 128 + ks * 32 + lk);
#pragma unroll
        for (int m = 0; m < 4; m++) {
            short8 af = *(const short8*)&Ts[(lrowBase + m * 16 + l15) * TS_STRIDE + ks * 32 + lk];
#pragma unroll
            for (int n = 0; n < 4; n++)
                acc[m][n] = __builtin_amdgcn_mfma_f32_16x16x32_bf16(af, bfr[n], acc[m][n], 0, 0, 0);
        }
    }

    // ---- epilogue: column stats + Z store (identical to standalone gemm) --------
    int rowBase = blockIdx.x * 128 + lrowBase;
#pragma unroll
    for (int n = 0; n < 4; n++) {
        float s = 0.f, ss = 0.f;
#pragma unroll
        for (int m = 0; m < 4; m++)
#pragma unroll
            for (int r = 0; r < 4; r++) {
                float v = acc[m][n][r];
                s += v;
                ss += v * v;
            }
        s += __shfl_xor(s, 16);
        ss += __shfl_xor(ss, 16);
        s += __shfl_xor(s, 32);
        ss += __shfl_xor(ss, 32);
        if ((lane & 48) == 0) {
            atomicAdd(&lstat[colBase + n * 16 + l15], s);
            atomicAdd(&lstat[128 + colBase + n * 16 + l15], ss);
        }
    }
    __syncthreads();
    partial[(size_t)blockIdx.x * 256 + tid] = lstat[tid];

#pragma unroll
    for (int m = 0; m < 4; m++) {
#pragma unroll
        for (int r = 0; r < 4; r++) {
            int row = rowBase + m * 16 + (lane >> 4) * 4 + r;
            if (row < M) {
#pragma unroll
                for (int n = 0; n < 4; n++)
                    Z[(size_t)row * 128 + colBase + n * 16 + l15] = f2b(acc[m][n][r]);
            }
        }
    }
}

// ================= MFMA GEMM (bf16): Z = f(A) @ W + column stats (gemm2) =========
template <int MODE>
__global__ __launch_bounds__(256) void mfma_gemm_kernel(
    const ushort* __restrict__ A, const ushort* __restrict__ Bt,
    const float* __restrict__ av, const float* __restrict__ bv,
    ushort* __restrict__ Z, float* __restrict__ partial, int M) {
    __shared__ float lstat[256];
    int tid = threadIdx.x;
    int lane = tid & 63;
    int wid = tid >> 6;
    int wr = wid >> 1, wc = wid & 1;
    int rowBase = blockIdx.x * 128 + wr * 64;
    int colBase = wc * 64;
    int l15 = lane & 15;
    int lk = (lane >> 4) * 8;

    short8 bfr[4][4];
#pragma unroll
    for (int n = 0; n < 4; n++)
#pragma unroll
        for (int ks = 0; ks < 4; ks++)
            bfr[n][ks] = *(const short8*)(Bt + (size_t)(colBase + n * 16 + l15) * 128 + ks * 32 + lk);

    f32x4 acc[4][4];
#pragma unroll
    for (int m = 0; m < 4; m++)
#pragma unroll
        for (int n = 0; n < 4; n++) acc[m][n] = (f32x4){0.f, 0.f, 0.f, 0.f};

#pragma unroll
    for (int ks = 0; ks < 4; ks++) {
        float a8[8], b8[8];
        if (MODE == 1) {
#pragma unroll
            for (int jj = 0; jj < 8; jj++) {
                a8[jj] = av[ks * 32 + lk + jj];
                b8[jj] = bv[ks * 32 + lk + jj];
            }
        }
#pragma unroll
        for (int m = 0; m < 4; m++) {
            int row = rowBase + m * 16 + l15;
            short8 af = {0, 0, 0, 0, 0, 0, 0, 0};
            if (row < M) {
                af = *(const short8*)(A + (size_t)row * 128 + ks * 32 + lk);
                if (MODE == 1) {
#pragma unroll
                    for (int jj = 0; jj < 8; jj++) {
                        float v = b2f((unsigned short)af[jj]);
                        v = fmaxf(fmaf(v, a8[jj], b8[jj]), 0.f);
                        af[jj] = (short)f2b(v);
                    }
                }
            }
#pragma unroll
            for (int n = 0; n < 4; n++)
                acc[m][n] = __builtin_amdgcn_mfma_f32_16x16x32_bf16(af, bfr[n][ks], acc[m][n], 0, 0, 0);
        }
    }

    lstat[tid] = 0.f;
    __syncthreads();
#pragma unroll
    for (int n = 0; n < 4; n++) {
        float s = 0.f, ss = 0.f;
#pragma unroll
        for (int m = 0; m < 4; m++)
#pragma unroll
            for (int r = 0; r < 4; r++) {
                float v = acc[m][n][r];
                s += v;
                ss += v * v;
            }
        s += __shfl_xor(s, 16);
        ss += __shfl_xor(ss, 16);
        s += __shfl_xor(s, 32);
        ss += __shfl_xor(ss, 32);
        if ((lane & 48) == 0) {
            atomicAdd(&lstat[colBase + n * 16 + l15], s);
            atomicAdd(&lstat[128 + colBase + n * 16 + l15], ss);
        }
    }
    __syncthreads();
    partial[(size_t)blockIdx.x * 256 + tid] = lstat[tid];

#pragma unroll
    for (int m = 0; m < 4; m++) {
#pragma unroll
        for (int r = 0; r < 4; r++) {
            int row = rowBase + m * 16 + (lane >> 4) * 4 + r;
            if (row < M) {
#pragma unroll
                for (int n = 0; n < 4; n++)
                    Z[(size_t)row * 128 + colBase + n * 16 + l15] = f2b(acc[m][n][r]);
            }
        }
    }
}

// ================= BN finalize =================
__global__ void fin_kernel(const float* __restrict__ partial, int nblk,
                           const float* __restrict__ gamma, const float* __restrict__ beta,
                           float* __restrict__ a, float* __restrict__ b, float invN) {
    int c = blockIdx.x;
    int t = threadIdx.x;
    float s = 0.f, ss = 0.f;
    for (int j = t; j < nblk; j += 64) {
        s += partial[(size_t)j * 256 + c];
        ss += partial[(size_t)j * 256 + 128 + c];
    }
    for (int off = 32; off >= 1; off >>= 1) {
        s += __shfl_down(s, off);
        ss += __shfl_down(ss, off);
    }
    if (t == 0) {
        float m = s * invN;
        float v = fmaxf(ss * invN - m * m, 0.f);
        float inv = rsqrtf(v + BN_EPS);
        float ac = gamma[c] * inv;
        a[c] = ac;
        b[c] = beta[c] - m * ac;
    }
}

// ================= pool + activation (+ Hact materialization) ====================
template <bool WRITE_H>
__global__ __launch_bounds__(512) void pool_act_kernel(const ushort* __restrict__ X,
                                                       const int* __restrict__ gptr,
                                                       const float* __restrict__ av,
                                                       const float* __restrict__ bv,
                                                       float* __restrict__ pooled,
                                                       ushort* __restrict__ hact) {
    __shared__ float red[8][132];
    int g = blockIdx.x, t = threadIdx.x;
    int tx = t & 15, ty = t >> 4;
    float a8[8], b8[8];
#pragma unroll
    for (int j = 0; j < 8; j++) {
        a8[j] = av[tx * 8 + j];
        b8[j] = bv[tx * 8 + j];
    }
    int r1 = gptr[g + 1];
    float acc[8] = {0.f, 0.f, 0.f, 0.f, 0.f, 0.f, 0.f, 0.f};
    const uint4* xp = (const uint4*)X;
    for (int r = gptr[g] + ty; r < r1; r += 32) {
        uint4 v = xp[(size_t)r * 16 + tx];
        unsigned wds[4] = {v.x, v.y, v.z, v.w};
        unsigned o[4];
#pragma unroll
        for (int q = 0; q < 4; q++) {
            float lo = __uint_as_float(wds[q] << 16);
            float hi = __uint_as_float(wds[q] & 0xffff0000u);
            lo = fmaxf(fmaf(lo, a8[2 * q], b8[2 * q]), 0.f);
            hi = fmaxf(fmaf(hi, a8[2 * q + 1], b8[2 * q + 1]), 0.f);
            acc[2 * q] += lo;
            acc[2 * q + 1] += hi;
            if (WRITE_H) o[q] = (unsigned)f2b(lo) | ((unsigned)f2b(hi) << 16);
        }
        if (WRITE_H) {
            uint4 ov = {o[0], o[1], o[2], o[3]};
            ((uint4*)hact)[(size_t)r * 16 + tx] = ov;
        }
    }
#pragma unroll
    for (int j = 0; j < 8; j++) {
        acc[j] += __shfl_xor(acc[j], 16);
        acc[j] += __shfl_xor(acc[j], 32);
    }
    int wave = t >> 6;
    if ((ty & 3) == 0) {
#pragma unroll
        for (int j = 0; j < 8; j++) red[wave][tx * 8 + j] = acc[j];
    }
    __syncthreads();
    if (t < 128) {
        float s = 0.f;
#pragma unroll
        for (int wv = 0; wv < 8; wv++) s += red[wv][t];
        pooled[(size_t)g * 128 + t] = s;
    }
}

// ================= score + log_softmax =================
__global__ void score_kernel(const float* __restrict__ pooled, const float* __restrict__ Wp,
                             const float* __restrict__ bp, float* __restrict__ out) {
    int g = blockIdx.x;
    int lane = threadIdx.x;
    int o = lane & 15, q = lane >> 4;
    float acc = 0.f;
    for (int i = 0; i < N_LAYERS + 1; i++) {
        const float* pr = pooled + (size_t)i * N_GRAPH * 128 + (size_t)g * 128;
        const float* wp = Wp + (size_t)i * 128 * 16;
#pragma unroll 8
        for (int d = q * 32; d < q * 32 + 32; d++) acc += pr[d] * wp[d * 16 + o];
    }
    acc += __shfl_xor(acc, 16);
    acc += __shfl_xor(acc, 32);
    float bsum = 0.f;
#pragma unroll
    for (int i = 0; i < N_LAYERS + 1; i++) bsum += bp[i * 16 + o];
    float s = acc + bsum;
    float m = s;
    for (int off = 8; off >= 1; off >>= 1) m = fmaxf(m, __shfl_xor(m, off, 16));
    float e = expf(s - m);
    float se = e;
    for (int off = 8; off >= 1; off >>= 1) se += __shfl_xor(se, off, 16);
    if (lane < 16) {
        out[g * 16 + o] = s - m - logf(se);
        out[(size_t)N_GRAPH * 16 + g * 16 + o] = s;
    }
}

extern "C" void kernel_launch(void* const* d_in, const int* in_sizes, int n_in,
                              void* d_out, int out_size, void* d_ws, size_t ws_size,
                              hipStream_t stream) {
    (void)in_sizes; (void)n_in; (void)out_size; (void)ws_size;
    const float* feat  = (const float*)d_in[0];
    const float* W1    = (const float*)d_in[1];
    const float* W2    = (const float*)d_in[2];
    const float* g_mlp = (const float*)d_in[3];
    const float* b_mlp = (const float*)d_in[4];
    const float* g_out = (const float*)d_in[5];
    const float* b_out = (const float*)d_in[6];
    const float* Wp    = (const float*)d_in[7];
    const float* bp    = (const float*)d_in[8];
    const int*   src   = (const int*)d_in[9];
    const int*   dst   = (const int*)d_in[10];
    const int*   gid   = (const int*)d_in[11];
    float* out = (float*)d_out;

    const int N = N_NODES, E = N_EDGES, G = N_GRAPH;
    char* w = (char*)d_ws;
    size_t off = 0;
    auto alloc = [&](size_t bytes) -> char* {
        char* p = w + off;
        off = (off + bytes + 255) & ~(size_t)255;
        return p;
    };
    ushort* X      = (ushort*)alloc((size_t)N * DIM * 2);  // layer-0 feats / raw gemm2 out
    ushort* Hact   = (ushort*)alloc((size_t)N * DIM * 2);  // activated h (bf16)
    ushort* Z      = (ushort*)alloc((size_t)N * DIM * 2);  // gemm1 output (aliased: bb)
    ushort* Wt     = (ushort*)alloc((size_t)8 * 128 * 128 * 2);
    int*    csr    = (int*)alloc((size_t)E * 4);
    int*    ptr    = (int*)alloc((size_t)(N + 1) * 4);
    int*    gcnt   = (int*)alloc(NB * 4);
    int*    bbase  = (int*)alloc(NB * 4);
    int*    gcur   = (int*)alloc(NB * 4);
    int*    gptr   = (int*)alloc((G + 1) * 4);
    float*  pooled = (float*)alloc((size_t)(N_LAYERS + 1) * G * DIM * 4);
    float*  partial= (float*)alloc((size_t)GEMM_BLOCKS * 256 * 4);
    float*  ab     = (float*)alloc(4 * 128 * 4);  // aZ bZ aX bX
    int*    bb     = (int*)Z;  // packed bucket buffer aliases Z (consumed before gemm1)

    const float invN = 1.f / (float)N;
    float* abZ = ab;
    float* abX = ab + 256;

    // ---- CSR build ----
    hipMemsetAsync(gcnt, 0, NB * 4, stream);
    hist512_kernel<<<256, 256, 0, stream>>>(dst, gcnt, E);
    scan512_kernel<<<1, NB, 0, stream>>>(gcnt, bbase, gcur, ptr);
    phaseA_kernel<<<(E + PA_CHUNK - 1) / PA_CHUNK, 256, 0, stream>>>(src, dst, gcur, bb, E);
    phaseB_kernel<<<NB, 256, 0, stream>>>(bb, bbase, gcnt, ptr, csr);
    gptr_kernel<<<3, 256, 0, stream>>>(gid, gptr, N, G);

    // ---- fused conversion + layer-0 readout ----
    cvtpool_kernel<<<G, 512, 0, stream>>>(feat, gptr, pooled, X);
    cvtw_kernel<<<1024, 128, 0, stream>>>(W1, W2, Wt);

    // ---- layers ----
    for (int i = 0; i < N_LAYERS; i++) {
        spmm_gemm_kernel<<<GEMM_BLOCKS, 256, 0, stream>>>(
            i == 0 ? X : Hact, ptr, csr, Wt + (size_t)i * 16384, Z, partial, N);
        fin_kernel<<<128, 64, 0, stream>>>(partial, GEMM_BLOCKS, g_mlp + (size_t)i * DIM,
                                           b_mlp + (size_t)i * DIM, abZ, abZ + 128, invN);
        mfma_gemm_kernel<1><<<GEMM_BLOCKS, 256, 0, stream>>>(
            Z, Wt + (size_t)(4 + i) * 16384, abZ, abZ + 128, X, partial, N);
        fin_kernel<<<128, 64, 0, stream>>>(partial, GEMM_BLOCKS, g_out + (size_t)i * DIM,
                                           b_out + (size_t)i * DIM, abX, abX + 128, invN);
        if (i < N_LAYERS - 1)
            pool_act_kernel<true><<<G, 512, 0, stream>>>(X, gptr, abX, abX + 128,
                                                         pooled + (size_t)(i + 1) * G * DIM, Hact);
        else
            pool_act_kernel<false><<<G, 512, 0, stream>>>(X, gptr, abX, abX + 128,
                                                          pooled + (size_t)(i + 1) * G * DIM, Hact);
    }
    score_kernel<<<G, 64, 0, stream>>>(pooled, Wp, bp, out);
}

// Round 12
// 611.280 us; speedup vs baseline: 1.1102x; 1.1102x over previous
//
#include <hip/hip_runtime.h>

#define N_NODES 100000
#define N_EDGES 1600000
#define DIM 128
#define N_GRAPH 512
#define N_LAYERS 4
#define BN_EPS 1e-5f
#define GEMM_BLOCKS ((N_NODES + 127) / 128)  // 782
#define SG_BLOCKS ((N_NODES + 63) / 64)      // 1563 (fused spmm+gemm1 tiles)
#define NB 512        // CSR buckets
#define BW 196        // nodes per bucket (512*196 = 100352 >= N)
#define PA_CHUNK 4096
#define TS_STRIDE 136 // ushorts per LDS row (272 B): bank-rotating, 16B-aligned

typedef __attribute__((ext_vector_type(8))) short short8;
typedef __attribute__((ext_vector_type(4))) float f32x4;

__device__ __forceinline__ float b2f(unsigned short u) {
    union { unsigned int i; float f; } x;
    x.i = ((unsigned int)u) << 16;
    return x.f;
}
__device__ __forceinline__ unsigned short f2b(float f) {
    union { float f; unsigned int i; } x;
    x.f = f;
    unsigned int r = x.i + 0x7FFFu + ((x.i >> 16) & 1u);  // RNE
    return (unsigned short)(r >> 16);
}

// ================= CSR build (bucketed, write-locality-friendly) =================
__global__ __launch_bounds__(256) void hist512_kernel(const int* __restrict__ dst,
                                                      int* __restrict__ gcnt, int E) {
    __shared__ int cnt[NB];
    int t = threadIdx.x;
    for (int i = t; i < NB; i += 256) cnt[i] = 0;
    __syncthreads();
    for (int e = blockIdx.x * 256 + t; e < E; e += 256 * 256)
        atomicAdd(&cnt[dst[e] / BW], 1);
    __syncthreads();
    for (int i = t; i < NB; i += 256)
        if (cnt[i]) atomicAdd(&gcnt[i], cnt[i]);
}

__global__ __launch_bounds__(NB) void scan512_kernel(const int* __restrict__ gcnt,
                                                     int* __restrict__ base,
                                                     int* __restrict__ gcur,
                                                     int* __restrict__ ptr) {
    __shared__ int tmp[NB];
    int t = threadIdx.x;
    int v = gcnt[t];
    tmp[t] = v;
    __syncthreads();
    int acc = v;
    for (int off = 1; off < NB; off <<= 1) {
        int add = (t >= off) ? tmp[t - off] : 0;
        __syncthreads();
        acc += add;
        tmp[t] = acc;
        __syncthreads();
    }
    int ex = acc - v;
    base[t] = ex;
    gcur[t] = ex;
    if (t == NB - 1) ptr[N_NODES] = ex + v;
}

// scatter packed (src | local_dst<<17) into bucket regions
__global__ __launch_bounds__(256) void phaseA_kernel(const int* __restrict__ src,
                                                     const int* __restrict__ dst,
                                                     int* __restrict__ gcur,
                                                     int* __restrict__ bb, int E) {
    __shared__ int cnt[NB];
    __shared__ int cur[NB];
    int t = threadIdx.x;
    int e0 = blockIdx.x * PA_CHUNK;
    for (int i = t; i < NB; i += 256) cnt[i] = 0;
    __syncthreads();
#pragma unroll
    for (int i = 0; i < PA_CHUNK / 256; i++) {
        int e = e0 + t + i * 256;
        if (e < E) atomicAdd(&cnt[dst[e] / BW], 1);
    }
    __syncthreads();
    for (int i = t; i < NB; i += 256) {
        int c = cnt[i];
        cur[i] = c ? atomicAdd(&gcur[i], c) : 0;
    }
    __syncthreads();
#pragma unroll
    for (int i = 0; i < PA_CHUNK / 256; i++) {
        int e = e0 + t + i * 256;
        if (e < E) {
            int d = dst[e];
            int b = d / BW;
            int pos = atomicAdd(&cur[b], 1);
            bb[pos] = src[e] | ((d - b * BW) << 17);
        }
    }
}

// per-bucket fine scatter; csr stores src*16 (uint4 units)
__global__ __launch_bounds__(256) void phaseB_kernel(const int* __restrict__ bb,
                                                     const int* __restrict__ base,
                                                     const int* __restrict__ gcnt,
                                                     int* __restrict__ ptr,
                                                     int* __restrict__ csr) {
    __shared__ int cnt[256];
    __shared__ int cur[256];
    __shared__ int tmp[256];
    int b = blockIdx.x, t = threadIdx.x;
    int n0 = b * BW;
    int e0 = base[b], ec = gcnt[b];
    cnt[t] = 0;
    __syncthreads();
    for (int j = t; j < ec; j += 256) atomicAdd(&cnt[bb[e0 + j] >> 17], 1);
    __syncthreads();
    int v = cnt[t];
    tmp[t] = v;
    __syncthreads();
    int acc = v;
    for (int off = 1; off < 256; off <<= 1) {
        int add = (t >= off) ? tmp[t - off] : 0;
        __syncthreads();
        acc += add;
        tmp[t] = acc;
        __syncthreads();
    }
    int ex = acc - v;
    int node = n0 + t;
    if (t < BW && node < N_NODES) ptr[node] = e0 + ex;
    cur[t] = e0 + ex;
    __syncthreads();
    for (int j = t; j < ec; j += 256) {
        int p = bb[e0 + j];
        int slot = atomicAdd(&cur[p >> 17], 1);
        csr[slot] = (p & 0x1FFFF) << 4;
    }
}

__global__ void gptr_kernel(const int* __restrict__ gid, int* __restrict__ gptr, int N, int G) {
    int g = blockIdx.x * 256 + threadIdx.x;
    if (g > G) return;
    int lo = 0, hi = N;
    while (lo < hi) {
        int mid = (lo + hi) >> 1;
        if (gid[mid] < g) lo = mid + 1; else hi = mid;
    }
    gptr[g] = lo;
}

// ================= fused f32 pool + bf16 convert (layer 0) =======================
__global__ __launch_bounds__(512) void cvtpool_kernel(const float* __restrict__ feat,
                                                      const int* __restrict__ gptr,
                                                      float* __restrict__ pooled,
                                                      ushort* __restrict__ X) {
    __shared__ float red[8][132];
    int g = blockIdx.x, t = threadIdx.x;
    int tx = t & 31, ty = t >> 5;
    int r1 = gptr[g + 1];
    float acc[4] = {0.f, 0.f, 0.f, 0.f};
    const float4* xp = (const float4*)feat;
    for (int r = gptr[g] + ty; r < r1; r += 16) {
        float4 v = xp[(size_t)r * 32 + tx];
        acc[0] += v.x; acc[1] += v.y; acc[2] += v.z; acc[3] += v.w;
        ushort4 u;
        u.x = f2b(v.x); u.y = f2b(v.y); u.z = f2b(v.z); u.w = f2b(v.w);
        ((ushort4*)X)[(size_t)r * 32 + tx] = u;
    }
#pragma unroll
    for (int j = 0; j < 4; j++) acc[j] += __shfl_xor(acc[j], 32);
    int wave = t >> 6;
    if ((ty & 1) == 0) {
#pragma unroll
        for (int j = 0; j < 4; j++) red[wave][tx * 4 + j] = acc[j];
    }
    __syncthreads();
    if (t < 128) {
        float s = 0.f;
#pragma unroll
        for (int wv = 0; wv < 8; wv++) s += red[wv][t];
        pooled[(size_t)g * 128 + t] = s;
    }
}

__global__ void cvtw_kernel(const float* __restrict__ W1, const float* __restrict__ W2,
                            ushort* __restrict__ Wt) {
    int blk = blockIdx.x;
    int mat = blk >> 7, k = blk & 127;
    int n = threadIdx.x;
    const float* W = (mat < 4) ? (W1 + (size_t)mat * 16384) : (W2 + (size_t)(mat - 4) * 16384);
    Wt[(size_t)mat * 16384 + n * 128 + k] = f2b(W[k * 128 + n]);
}

// ================= fused SpMM + GEMM1 (64-row tiles): Z = (gather X) @ W1 ========
__device__ __forceinline__ void accum8(float* acc, uint4 v) {
    unsigned w[4] = {v.x, v.y, v.z, v.w};
#pragma unroll
    for (int q = 0; q < 4; q++) {
        acc[2 * q]     += __uint_as_float(w[q] << 16);
        acc[2 * q + 1] += __uint_as_float(w[q] & 0xffff0000u);
    }
}

__global__ __launch_bounds__(256) void spmm_gemm_kernel(
    const ushort* __restrict__ X, const int* __restrict__ ptr,
    const int* __restrict__ csr, const ushort* __restrict__ Bt,
    ushort* __restrict__ Z, float* __restrict__ partial, int M) {
    __shared__ ushort Ts[64 * TS_STRIDE];
    __shared__ float lstat[256];
    int tid = threadIdx.x;
    const uint4* hp = (const uint4*)X;

    // ---- Phase 1: gather 64 dst rows into LDS (16 lanes/node, 4 rounds) --------
    {
        int l = tid & 15, slot = tid >> 4;
#pragma unroll 1
        for (int rr = 0; rr < 4; rr++) {
            int lr = rr * 16 + slot;
            int node = blockIdx.x * 64 + lr;
            float acc[8] = {0.f, 0.f, 0.f, 0.f, 0.f, 0.f, 0.f, 0.f};
            if (node < M) {
                accum8(acc, hp[(size_t)node * 16 + l]);
                int j = ptr[node], s1 = ptr[node + 1];
                for (; j + 7 < s1; j += 8) {
                    int idx[8];
                    uint4 v[8];
#pragma unroll
                    for (int q = 0; q < 8; q++) idx[q] = csr[j + q];
#pragma unroll
                    for (int q = 0; q < 8; q++) v[q] = hp[(size_t)(idx[q] + l)];
#pragma unroll
                    for (int q = 0; q < 8; q++) accum8(acc, v[q]);
                }
                for (; j + 1 < s1; j += 2) {
                    int i0 = csr[j], i1 = csr[j + 1];
                    uint4 v0 = hp[(size_t)(i0 + l)];
                    uint4 v1 = hp[(size_t)(i1 + l)];
                    accum8(acc, v0);
                    accum8(acc, v1);
                }
                if (j < s1) accum8(acc, hp[(size_t)(csr[j] + l)]);
            }
            uint4 o;
            unsigned* op = (unsigned*)&o;
#pragma unroll
            for (int q = 0; q < 4; q++)
                op[q] = (unsigned)f2b(acc[2 * q]) | ((unsigned)f2b(acc[2 * q + 1]) << 16);
            *(uint4*)&Ts[lr * TS_STRIDE + l * 8] = o;
        }
    }
    lstat[tid] = 0.f;
    __syncthreads();

    // ---- Phase 2: MFMA from LDS (4 waves, each 32 rows x 64 cols, B preloaded) --
    int lane = tid & 63;
    int wid = tid >> 6;
    int wr = wid >> 1, wc = wid & 1;
    int colBase = wc * 64;
    int l15 = lane & 15;
    int lk = (lane >> 4) * 8;

    short8 bfr[4][4];
#pragma unroll
    for (int n = 0; n < 4; n++)
#pragma unroll
        for (int ks = 0; ks < 4; ks++)
            bfr[n][ks] = *(const short8*)(Bt + (size_t)(colBase + n * 16 + l15) * 128 + ks * 32 + lk);

    f32x4 acc[2][4];
#pragma unroll
    for (int m = 0; m < 2; m++)
#pragma unroll
        for (int n = 0; n < 4; n++) acc[m][n] = (f32x4){0.f, 0.f, 0.f, 0.f};

#pragma unroll
    for (int ks = 0; ks < 4; ks++) {
#pragma unroll
        for (int m = 0; m < 2; m++) {
            short8 af = *(const short8*)&Ts[(wr * 32 + m * 16 + l15) * TS_STRIDE + ks * 32 + lk];
#pragma unroll
            for (int n = 0; n < 4; n++)
                acc[m][n] = __builtin_amdgcn_mfma_f32_16x16x32_bf16(af, bfr[n][ks], acc[m][n], 0, 0, 0);
        }
    }

    // ---- epilogue: column stats + Z store ---------------------------------------
#pragma unroll
    for (int n = 0; n < 4; n++) {
        float s = 0.f, ss = 0.f;
#pragma unroll
        for (int m = 0; m < 2; m++)
#pragma unroll
            for (int r = 0; r < 4; r++) {
                float v = acc[m][n][r];
                s += v;
                ss += v * v;
            }
        s += __shfl_xor(s, 16);
        ss += __shfl_xor(ss, 16);
        s += __shfl_xor(s, 32);
        ss += __shfl_xor(ss, 32);
        if ((lane & 48) == 0) {
            atomicAdd(&lstat[colBase + n * 16 + l15], s);
            atomicAdd(&lstat[128 + colBase + n * 16 + l15], ss);
        }
    }
    __syncthreads();
    partial[(size_t)blockIdx.x * 256 + tid] = lstat[tid];

#pragma unroll
    for (int m = 0; m < 2; m++) {
#pragma unroll
        for (int r = 0; r < 4; r++) {
            int row = blockIdx.x * 64 + wr * 32 + m * 16 + (lane >> 4) * 4 + r;
            if (row < M) {
#pragma unroll
                for (int n = 0; n < 4; n++)
                    Z[(size_t)row * 128 + colBase + n * 16 + l15] = f2b(acc[m][n][r]);
            }
        }
    }
}

// ================= MFMA GEMM (bf16): Z = f(A) @ W + column stats (gemm2) =========
template <int MODE>
__global__ __launch_bounds__(256) void mfma_gemm_kernel(
    const ushort* __restrict__ A, const ushort* __restrict__ Bt,
    const float* __restrict__ av, const float* __restrict__ bv,
    ushort* __restrict__ Z, float* __restrict__ partial, int M) {
    __shared__ float lstat[256];
    int tid = threadIdx.x;
    int lane = tid & 63;
    int wid = tid >> 6;
    int wr = wid >> 1, wc = wid & 1;
    int rowBase = blockIdx.x * 128 + wr * 64;
    int colBase = wc * 64;
    int l15 = lane & 15;
    int lk = (lane >> 4) * 8;

    short8 bfr[4][4];
#pragma unroll
    for (int n = 0; n < 4; n++)
#pragma unroll
        for (int ks = 0; ks < 4; ks++)
            bfr[n][ks] = *(const short8*)(Bt + (size_t)(colBase + n * 16 + l15) * 128 + ks * 32 + lk);

    f32x4 acc[4][4];
#pragma unroll
    for (int m = 0; m < 4; m++)
#pragma unroll
        for (int n = 0; n < 4; n++) acc[m][n] = (f32x4){0.f, 0.f, 0.f, 0.f};

#pragma unroll
    for (int ks = 0; ks < 4; ks++) {
        float a8[8], b8[8];
        if (MODE == 1) {
#pragma unroll
            for (int jj = 0; jj < 8; jj++) {
                a8[jj] = av[ks * 32 + lk + jj];
                b8[jj] = bv[ks * 32 + lk + jj];
            }
        }
#pragma unroll
        for (int m = 0; m < 4; m++) {
            int row = rowBase + m * 16 + l15;
            short8 af = {0, 0, 0, 0, 0, 0, 0, 0};
            if (row < M) {
                af = *(const short8*)(A + (size_t)row * 128 + ks * 32 + lk);
                if (MODE == 1) {
#pragma unroll
                    for (int jj = 0; jj < 8; jj++) {
                        float v = b2f((unsigned short)af[jj]);
                        v = fmaxf(fmaf(v, a8[jj], b8[jj]), 0.f);
                        af[jj] = (short)f2b(v);
                    }
                }
            }
#pragma unroll
            for (int n = 0; n < 4; n++)
                acc[m][n] = __builtin_amdgcn_mfma_f32_16x16x32_bf16(af, bfr[n][ks], acc[m][n], 0, 0, 0);
        }
    }

    lstat[tid] = 0.f;
    __syncthreads();
#pragma unroll
    for (int n = 0; n < 4; n++) {
        float s = 0.f, ss = 0.f;
#pragma unroll
        for (int m = 0; m < 4; m++)
#pragma unroll
            for (int r = 0; r < 4; r++) {
                float v = acc[m][n][r];
                s += v;
                ss += v * v;
            }
        s += __shfl_xor(s, 16);
        ss += __shfl_xor(ss, 16);
        s += __shfl_xor(s, 32);
        ss += __shfl_xor(ss, 32);
        if ((lane & 48) == 0) {
            atomicAdd(&lstat[colBase + n * 16 + l15], s);
            atomicAdd(&lstat[128 + colBase + n * 16 + l15], ss);
        }
    }
    __syncthreads();
    partial[(size_t)blockIdx.x * 256 + tid] = lstat[tid];

#pragma unroll
    for (int m = 0; m < 4; m++) {
#pragma unroll
        for (int r = 0; r < 4; r++) {
            int row = rowBase + m * 16 + (lane >> 4) * 4 + r;
            if (row < M) {
#pragma unroll
                for (int n = 0; n < 4; n++)
                    Z[(size_t)row * 128 + colBase + n * 16 + l15] = f2b(acc[m][n][r]);
            }
        }
    }
}

// ================= BN finalize =================
__global__ void fin_kernel(const float* __restrict__ partial, int nblk,
                           const float* __restrict__ gamma, const float* __restrict__ beta,
                           float* __restrict__ a, float* __restrict__ b, float invN) {
    int c = blockIdx.x;
    int t = threadIdx.x;
    float s = 0.f, ss = 0.f;
    for (int j = t; j < nblk; j += 64) {
        s += partial[(size_t)j * 256 + c];
        ss += partial[(size_t)j * 256 + 128 + c];
    }
    for (int off = 32; off >= 1; off >>= 1) {
        s += __shfl_down(s, off);
        ss += __shfl_down(ss, off);
    }
    if (t == 0) {
        float m = s * invN;
        float v = fmaxf(ss * invN - m * m, 0.f);
        float inv = rsqrtf(v + BN_EPS);
        float ac = gamma[c] * inv;
        a[c] = ac;
        b[c] = beta[c] - m * ac;
    }
}

// ================= pool + activation (+ Hact materialization) ====================
template <bool WRITE_H>
__global__ __launch_bounds__(512) void pool_act_kernel(const ushort* __restrict__ X,
                                                       const int* __restrict__ gptr,
                                                       const float* __restrict__ av,
                                                       const float* __restrict__ bv,
                                                       float* __restrict__ pooled,
                                                       ushort* __restrict__ hact) {
    __shared__ float red[8][132];
    int g = blockIdx.x, t = threadIdx.x;
    int tx = t & 15, ty = t >> 4;
    float a8[8], b8[8];
#pragma unroll
    for (int j = 0; j < 8; j++) {
        a8[j] = av[tx * 8 + j];
        b8[j] = bv[tx * 8 + j];
    }
    int r1 = gptr[g + 1];
    float acc[8] = {0.f, 0.f, 0.f, 0.f, 0.f, 0.f, 0.f, 0.f};
    const uint4* xp = (const uint4*)X;
    for (int r = gptr[g] + ty; r < r1; r += 32) {
        uint4 v = xp[(size_t)r * 16 + tx];
        unsigned wds[4] = {v.x, v.y, v.z, v.w};
        unsigned o[4];
#pragma unroll
        for (int q = 0; q < 4; q++) {
            float lo = __uint_as_float(wds[q] << 16);
            float hi = __uint_as_float(wds[q] & 0xffff0000u);
            lo = fmaxf(fmaf(lo, a8[2 * q], b8[2 * q]), 0.f);
            hi = fmaxf(fmaf(hi, a8[2 * q + 1], b8[2 * q + 1]), 0.f);
            acc[2 * q] += lo;
            acc[2 * q + 1] += hi;
            if (WRITE_H) o[q] = (unsigned)f2b(lo) | ((unsigned)f2b(hi) << 16);
        }
        if (WRITE_H) {
            uint4 ov = {o[0], o[1], o[2], o[3]};
            ((uint4*)hact)[(size_t)r * 16 + tx] = ov;
        }
    }
#pragma unroll
    for (int j = 0; j < 8; j++) {
        acc[j] += __shfl_xor(acc[j], 16);
        acc[j] += __shfl_xor(acc[j], 32);
    }
    int wave = t >> 6;
    if ((ty & 3) == 0) {
#pragma unroll
        for (int j = 0; j < 8; j++) red[wave][tx * 8 + j] = acc[j];
    }
    __syncthreads();
    if (t < 128) {
        float s = 0.f;
#pragma unroll
        for (int wv = 0; wv < 8; wv++) s += red[wv][t];
        pooled[(size_t)g * 128 + t] = s;
    }
}

// ================= score + log_softmax =================
__global__ void score_kernel(const float* __restrict__ pooled, const float* __restrict__ Wp,
                             const float* __restrict__ bp, float* __restrict__ out) {
    int g = blockIdx.x;
    int lane = threadIdx.x;
    int o = lane & 15, q = lane >> 4;
    float acc = 0.f;
    for (int i = 0; i < N_LAYERS + 1; i++) {
        const float* pr = pooled + (size_t)i * N_GRAPH * 128 + (size_t)g * 128;
        const float* wp = Wp + (size_t)i * 128 * 16;
#pragma unroll 8
        for (int d = q * 32; d < q * 32 + 32; d++) acc += pr[d] * wp[d * 16 + o];
    }
    acc += __shfl_xor(acc, 16);
    acc += __shfl_xor(acc, 32);
    float bsum = 0.f;
#pragma unroll
    for (int i = 0; i < N_LAYERS + 1; i++) bsum += bp[i * 16 + o];
    float s = acc + bsum;
    float m = s;
    for (int off = 8; off >= 1; off >>= 1) m = fmaxf(m, __shfl_xor(m, off, 16));
    float e = expf(s - m);
    float se = e;
    for (int off = 8; off >= 1; off >>= 1) se += __shfl_xor(se, off, 16);
    if (lane < 16) {
        out[g * 16 + o] = s - m - logf(se);
        out[(size_t)N_GRAPH * 16 + g * 16 + o] = s;
    }
}

extern "C" void kernel_launch(void* const* d_in, const int* in_sizes, int n_in,
                              void* d_out, int out_size, void* d_ws, size_t ws_size,
                              hipStream_t stream) {
    (void)in_sizes; (void)n_in; (void)out_size; (void)ws_size;
    const float* feat  = (const float*)d_in[0];
    const float* W1    = (const float*)d_in[1];
    const float* W2    = (const float*)d_in[2];
    const float* g_mlp = (const float*)d_in[3];
    const float* b_mlp = (const float*)d_in[4];
    const float* g_out = (const float*)d_in[5];
    const float* b_out = (const float*)d_in[6];
    const float* Wp    = (const float*)d_in[7];
    const float* bp    = (const float*)d_in[8];
    const int*   src   = (const int*)d_in[9];
    const int*   dst   = (const int*)d_in[10];
    const int*   gid   = (const int*)d_in[11];
    float* out = (float*)d_out;

    const int N = N_NODES, E = N_EDGES, G = N_GRAPH;
    char* w = (char*)d_ws;
    size_t off = 0;
    auto alloc = [&](size_t bytes) -> char* {
        char* p = w + off;
        off = (off + bytes + 255) & ~(size_t)255;
        return p;
    };
    ushort* X      = (ushort*)alloc((size_t)N * DIM * 2);  // layer-0 feats / raw gemm2 out
    ushort* Hact   = (ushort*)alloc((size_t)N * DIM * 2);  // activated h (bf16)
    ushort* Z      = (ushort*)alloc((size_t)N * DIM * 2);  // gemm1 output (aliased: bb)
    ushort* Wt     = (ushort*)alloc((size_t)8 * 128 * 128 * 2);
    int*    csr    = (int*)alloc((size_t)E * 4);
    int*    ptr    = (int*)alloc((size_t)(N + 1) * 4);
    int*    gcnt   = (int*)alloc(NB * 4);
    int*    bbase  = (int*)alloc(NB * 4);
    int*    gcur   = (int*)alloc(NB * 4);
    int*    gptr   = (int*)alloc((G + 1) * 4);
    float*  pooled = (float*)alloc((size_t)(N_LAYERS + 1) * G * DIM * 4);
    float*  partial= (float*)alloc((size_t)SG_BLOCKS * 256 * 4);
    float*  ab     = (float*)alloc(4 * 128 * 4);  // aZ bZ aX bX
    int*    bb     = (int*)Z;  // packed bucket buffer aliases Z (consumed before gemm1)

    const float invN = 1.f / (float)N;
    float* abZ = ab;
    float* abX = ab + 256;

    // ---- CSR build ----
    hipMemsetAsync(gcnt, 0, NB * 4, stream);
    hist512_kernel<<<256, 256, 0, stream>>>(dst, gcnt, E);
    scan512_kernel<<<1, NB, 0, stream>>>(gcnt, bbase, gcur, ptr);
    phaseA_kernel<<<(E + PA_CHUNK - 1) / PA_CHUNK, 256, 0, stream>>>(src, dst, gcur, bb, E);
    phaseB_kernel<<<NB, 256, 0, stream>>>(bb, bbase, gcnt, ptr, csr);
    gptr_kernel<<<3, 256, 0, stream>>>(gid, gptr, N, G);

    // ---- fused conversion + layer-0 readout ----
    cvtpool_kernel<<<G, 512, 0, stream>>>(feat, gptr, pooled, X);
    cvtw_kernel<<<1024, 128, 0, stream>>>(W1, W2, Wt);

    // ---- layers ----
    for (int i = 0; i < N_LAYERS; i++) {
        spmm_gemm_kernel<<<SG_BLOCKS, 256, 0, stream>>>(
            i == 0 ? X : Hact, ptr, csr, Wt + (size_t)i * 16384, Z, partial, N);
        fin_kernel<<<128, 64, 0, stream>>>(partial, SG_BLOCKS, g_mlp + (size_t)i * DIM,
                                           b_mlp + (size_t)i * DIM, abZ, abZ + 128, invN);
        mfma_gemm_kernel<1><<<GEMM_BLOCKS, 256, 0, stream>>>(
            Z, Wt + (size_t)(4 + i) * 16384, abZ, abZ + 128, X, partial, N);
        fin_kernel<<<128, 64, 0, stream>>>(partial, GEMM_BLOCKS, g_out + (size_t)i * DIM,
                                           b_out + (size_t)i * DIM, abX, abX + 128, invN);
        if (i < N_LAYERS - 1)
            pool_act_kernel<true><<<G, 512, 0, stream>>>(X, gptr, abX, abX + 128,
                                                         pooled + (size_t)(i + 1) * G * DIM, Hact);
        else
            pool_act_kernel<false><<<G, 512, 0, stream>>>(X, gptr, abX, abX + 128,
                                                          pooled + (size_t)(i + 1) * G * DIM, Hact);
    }
    score_kernel<<<G, 64, 0, stream>>>(pooled, Wp, bp, out);
}